// Round 6
// baseline (788.986 us; speedup 1.0000x reference)
//
#include <hip/hip_runtime.h>
#include <hip/hip_bf16.h>

// GNN: 2-layer GraphConv (DGL norm='both'), N=100000, E=1600000.
// Round 20: scatter-to-LDS sliced agg64. r17/r19 proved pinned slices stay
// L2-resident (FETCH 154->42MB) but gather-reduce slicing loses on sequential
// dependent chains + reduce trees. This round: block = (bucket, slice);
// stream the bucket's csrc CONTIGUOUSLY (entries keep sort2's packed
// src|dstlocal<<17 -> row for free), gather 32B slice rows from the pinned
// h1 plane (slice=blockIdx&3 -> XCD k runs slice k&3), ds_add_f32 into an
// 8.7KB LDS tile [128][17] (+1 pad: random rows -> ~2-way conflicts, free).
// No shfls, no dependent chains (edges independent -> pipelined), coalesced
// epilogue. agg32 masks SRCMASK on use. gemm1 stores h1 slice-major
// [4][N][16], gemm2 reads x2 slice-major (both r17-verified). CSR build
// unchanged (zero global atomics). Aliasing unchanged: ebuf/sbuf/soffs die
// at sort2, before agg64sc writes x2.

#define BSH 7                 // 128 nodes per bucket
#define BNODES 128
#define SRCMASK 0x1FFFF       // src < 131072
#define CAP 2560              // csrc bucket capacity (mean 2048, sigma~45)
#define CHUNK 4096            // edges per place-block (391 blocks)

__device__ __forceinline__ unsigned short f2bf(float f) {
    unsigned int u = __float_as_uint(f);
    return (unsigned short)((u + 0x7FFFu + ((u >> 16) & 1u)) >> 16);  // RNE
}

__device__ __forceinline__ float bflo(unsigned int u) {
    return __uint_as_float(u << 16);
}
__device__ __forceinline__ float bfhi(unsigned int u) {
    return __uint_as_float(u & 0xFFFF0000u);
}

// ---------------- place: block-local dual counting sort ---------------------
__global__ __launch_bounds__(1024) void k_place(const int* __restrict__ src,
        const int* __restrict__ dst, int* __restrict__ ebuf,
        unsigned char* __restrict__ sbuf, int* __restrict__ offs,
        int* __restrict__ soffs, int E) {
    __shared__ int lh[800], s[800];
    int t = threadIdx.x;
    int e0 = blockIdx.x * CHUNK;
    int e1 = min(e0 + CHUNK, E);
    if (t < 800) lh[t] = 0;
    __syncthreads();
    for (int i = e0 + t; i < e1; i += 1024) {
        atomicAdd(&lh[dst[i] >> BSH], 0x10000);
        atomicAdd(&lh[src[i] >> BSH], 1);
    }
    __syncthreads();
    if (t < 800) s[t] = lh[t];
    __syncthreads();
    for (int o = 1; o < 800; o <<= 1) {            // packed inclusive scan
        int u = (t < 800 && t >= o) ? s[t - o] : 0;
        __syncthreads();
        if (t < 800) s[t] += u;
        __syncthreads();
    }
    int obase = blockIdx.x * 801;
    if (t < 800) {
        int incl = s[t], c = lh[t];
        int bd = (incl >> 16) - (c >> 16);         // exclusive dst base
        int bs = (incl & 0xFFFF) - (c & 0xFFFF);   // exclusive src base
        offs[obase + t] = bd;
        soffs[obase + t] = bs;
        s[t] = (bd << 16) | bs;                    // packed cursors
    }
    if (t == 0) { offs[obase + 800] = e1 - e0; soffs[obase + 800] = e1 - e0; }
    __syncthreads();
    for (int i = e0 + t; i < e1; i += 1024) {
        int sv = src[i], d = dst[i];               // L2-hot from phase 1
        int pd = atomicAdd(&s[d >> BSH], 0x10000) >> 16;
        ebuf[e0 + pd] = sv | ((d & (BNODES - 1)) << 17);
        int ps = atomicAdd(&s[sv >> BSH], 1) & 0xFFFF;
        sbuf[e0 + ps] = (unsigned char)(sv & (BNODES - 1));
    }
}

// ---------------- sort2: segments -> CSR + nI + nO (no global atomics) ------
// csrc now keeps the FULL packed entry (src | dstlocal<<17): agg64sc needs
// the row; agg32 masks SRCMASK on use.
__global__ __launch_bounds__(1024) void k_sort2(const int* __restrict__ ebuf,
        const unsigned char* __restrict__ sbuf, const int* __restrict__ offs,
        const int* __restrict__ soffs, int* __restrict__ csrc,
        int* __restrict__ ostart, int* __restrict__ oend,
        float* __restrict__ nI, float* __restrict__ nO, int n, int NBLK) {
    __shared__ int cnt[BNODES], cur[BNODES], s[BNODES], scnt[BNODES];
    __shared__ int segst[400], segen[400], sst[400], sen[400];
    int t = threadIdx.x, b = blockIdx.x;
    if (t < NBLK) {
        segst[t] = t * CHUNK + offs[t * 801 + b];
        segen[t] = t * CHUNK + offs[t * 801 + b + 1];
        sst[t]   = t * CHUNK + soffs[t * 801 + b];
        sen[t]   = t * CHUNK + soffs[t * 801 + b + 1];
    }
    if (t < BNODES) { cnt[t] = 0; scnt[t] = 0; }
    __syncthreads();
    int grp = t >> 3, ln = t & 7;                  // 128 groups x 8 lanes
    for (int sg = grp; sg < NBLK; sg += 128) {
        int en = segen[sg];
        for (int i = segst[sg] + ln; i < en; i += 8)
            atomicAdd(&cnt[ebuf[i] >> 17], 1);
        int en2 = sen[sg];
        for (int i = sst[sg] + ln; i < en2; i += 8)
            atomicAdd(&scnt[sbuf[i]], 1);
    }
    __syncthreads();
    if (t < BNODES) s[t] = cnt[t];
    __syncthreads();
    for (int o = 1; o < BNODES; o <<= 1) {
        int u = (t < BNODES && t >= o) ? s[t - o] : 0;
        __syncthreads();
        if (t < BNODES) s[t] += u;
        __syncthreads();
    }
    if (t < BNODES) {
        int e0 = b * CAP;
        int st = e0 + s[t] - cnt[t];
        cur[t] = st;
        int g = b * BNODES + t;
        if (g < n) {
            ostart[g] = st;
            oend[g] = e0 + s[t];
            nI[g] = rsqrtf(fmaxf((float)cnt[t], 1.0f));
            nO[g] = rsqrtf(fmaxf((float)scnt[t], 1.0f));
        }
    }
    __syncthreads();
    for (int sg = grp; sg < NBLK; sg += 128) {
        int en = segen[sg];
        for (int i = segst[sg] + ln; i < en; i += 8) {
            int p = ebuf[i];                       // L2-hot from pass 1
            int pos = atomicAdd(&cur[p >> 17], 1);
            csrc[pos] = p;                         // keep packed src+row
        }
    }
}

// ---------------- GEMM1: h1(bf16, slice-major [4][N][16]) -------------------
__global__ __launch_bounds__(256) void k_gemm1(const float* __restrict__ x,
                        const float* __restrict__ W1, const float* __restrict__ nO,
                        unsigned short* __restrict__ h1, int n) {
    __shared__ float sX[64 * 132];
    __shared__ float sW[128 * 64];
    const int t = threadIdx.x;
    {
        const float4* W4 = (const float4*)W1;
        float4* sW4 = (float4*)sW;
#pragma unroll
        for (int i = 0; i < 8; i++) sW4[t + 256 * i] = W4[t + 256 * i];
    }
    const int rowbase = blockIdx.x * 64;
    {
        const float4* x4 = (const float4*)x;
        float4* sX4 = (float4*)sX;
#pragma unroll
        for (int i = 0; i < 8; i++) {
            int f = t + 256 * i;
            int row = f >> 5, kc = f & 31;
            int grow = rowbase + row;
            float4 v = make_float4(0.f, 0.f, 0.f, 0.f);
            if (grow < n) v = x4[(size_t)grow * 32 + kc];
            sX4[row * 33 + kc] = v;
        }
    }
    __syncthreads();
    const int lane = t & 63, wv = t >> 6;
    const int rg = lane >> 2, cg = lane & 3;
    const int c0 = wv * 16 + cg * 4;
    float acc[4][4] = {};
    for (int kk = 0; kk < 128; kk += 4) {
        float xr[4][4], wr[4][4];
#pragma unroll
        for (int i = 0; i < 4; i++)
            *(float4*)xr[i] = *(const float4*)&sX[(rg + 16 * i) * 132 + kk];
#pragma unroll
        for (int j = 0; j < 4; j++)
            *(float4*)wr[j] = *(const float4*)&sW[(kk + j) * 64 + c0];
#pragma unroll
        for (int j = 0; j < 4; j++)
#pragma unroll
            for (int i = 0; i < 4; i++)
#pragma unroll
                for (int c = 0; c < 4; c++)
                    acc[i][c] = fmaf(xr[i][j], wr[j][c], acc[i][c]);
    }
    const size_t pl = (size_t)n * 16;              // slice plane (ushorts)
#pragma unroll
    for (int i = 0; i < 4; i++) {
        int grow = rowbase + rg + 16 * i;
        if (grow < n) {
            float nf = nO[grow];
            ushort4 o;
            o.x = f2bf(acc[i][0] * nf); o.y = f2bf(acc[i][1] * nf);
            o.z = f2bf(acc[i][2] * nf); o.w = f2bf(acc[i][3] * nf);
            // slice = wv, in-slice col = cg*4
            *(ushort4*)&h1[(size_t)wv * pl + (size_t)grow * 16 + cg * 4] = o;
        }
    }
}

// ---------------- agg1 scatter: block = (bucket, slice), ds_add tile --------
// slice = blockIdx&3 (XCD k=bid%8 runs slice k&3 -> 3.2MB h1 plane resident).
// 4-lane group per edge: csrc broadcast-load (contiguous stream), uint2
// gather of 32B slice row, 4 ds_add_f32 into tile[row][17-stride]. Edges
// independent -> pipelined; no shfls. Epilogue: relu/bias/nI, coalesced
// float4 stores to slice-major x2.
__global__ __launch_bounds__(256) void k_agg64sc(const unsigned short* __restrict__ h,
        const int* __restrict__ csrc, const int* __restrict__ oend,
        const float* __restrict__ nI, const float* __restrict__ b1,
        float* __restrict__ x2, int n) {
    __shared__ float tile[BNODES * 17];
    const int s = blockIdx.x & 3;
    const int b = blockIdx.x >> 2;
    const int t = threadIdx.x;
    for (int i = t; i < BNODES * 17; i += 256) tile[i] = 0.f;
    const int e0 = b * CAP;
    const int last = min(b * BNODES + BNODES - 1, n - 1);
    const int eend = oend[last];
    __syncthreads();
    const int g = t >> 2, q = t & 3;               // 64 groups x 4 lanes
    const unsigned short* hs = h + (size_t)s * n * 16;
    for (int i = e0 + g; i < eend; i += 64) {
        int p = csrc[i];
        int srcv = p & SRCMASK;
        int row = (p >> 17) & (BNODES - 1);
        uint2 u = *(const uint2*)&hs[(size_t)srcv * 16 + q * 4];
        float* tr = &tile[row * 17 + q * 4];
        atomicAdd(&tr[0], bflo(u.x));
        atomicAdd(&tr[1], bfhi(u.x));
        atomicAdd(&tr[2], bflo(u.y));
        atomicAdd(&tr[3], bfhi(u.y));
    }
    __syncthreads();
    float* x2s = x2 + (size_t)s * n * 16;
    const int base = b * BNODES;
    const float4 bb = *(const float4*)&b1[s * 16 + (t & 3) * 4];
#pragma unroll
    for (int r = 0; r < 2; r++) {
        int i4 = t + 256 * r;                      // 512 float4 = 128x16
        int row = i4 >> 2, c4 = (i4 & 3) * 4;
        int node = base + row;
        if (node < n) {
            float ni = nI[node];
            const float* tr = &tile[row * 17 + c4];
            float4 o;
            o.x = fmaxf(fmaf(tr[0], ni, bb.x), 0.f);
            o.y = fmaxf(fmaf(tr[1], ni, bb.y), 0.f);
            o.z = fmaxf(fmaf(tr[2], ni, bb.z), 0.f);
            o.w = fmaxf(fmaf(tr[3], ni, bb.w), 0.f);
            *(float4*)&x2s[(size_t)node * 16 + c4] = o;
        }
    }
}

// ---------------- GEMM2: reads slice-major x2 [4][N][16] --------------------
__global__ __launch_bounds__(256) void k_gemm2(const float* __restrict__ x2,
                        const float* __restrict__ W2, const float* __restrict__ nO,
                        unsigned short* __restrict__ h2, int n) {
    __shared__ float sX[128 * 68];
    __shared__ float sW[64 * 32];
    const int t = threadIdx.x;
    {
        const float4* W4 = (const float4*)W2;
        float4* sW4 = (float4*)sW;
#pragma unroll
        for (int i = 0; i < 2; i++) sW4[t + 256 * i] = W4[t + 256 * i];
    }
    const int rowbase = blockIdx.x * 128;
    const size_t n4 = (size_t)n * 4;               // slice plane in float4
    {
        const float4* x4 = (const float4*)x2;
        float4* sX4 = (float4*)sX;
#pragma unroll
        for (int i = 0; i < 8; i++) {
            int f = t + 256 * i;
            int row = f >> 4, kc = f & 15;
            int grow = rowbase + row;
            float4 v = make_float4(0.f, 0.f, 0.f, 0.f);
            if (grow < n)
                v = x4[(size_t)(kc >> 2) * n4 + (size_t)grow * 4 + (kc & 3)];
            sX4[row * 17 + kc] = v;
        }
    }
    __syncthreads();
    const int lane = t & 63, wv = t >> 6;
    const int whalf = wv >> 1, chalf = wv & 1;
    const int rg = lane >> 2, cg = lane & 3;
    const int c0 = chalf * 16 + cg * 4;
    const int rloc = whalf * 64 + rg;
    float acc[4][4] = {};
    for (int kk = 0; kk < 64; kk += 4) {
        float xr[4][4], wr[4][4];
#pragma unroll
        for (int i = 0; i < 4; i++)
            *(float4*)xr[i] = *(const float4*)&sX[(rloc + 16 * i) * 68 + kk];
#pragma unroll
        for (int j = 0; j < 4; j++)
            *(float4*)wr[j] = *(const float4*)&sW[(kk + j) * 32 + c0];
#pragma unroll
        for (int j = 0; j < 4; j++)
#pragma unroll
            for (int i = 0; i < 4; i++)
#pragma unroll
                for (int c = 0; c < 4; c++)
                    acc[i][c] = fmaf(xr[i][j], wr[j][c], acc[i][c]);
    }
#pragma unroll
    for (int i = 0; i < 4; i++) {
        int grow = rowbase + rloc + 16 * i;
        if (grow < n) {
            float nf = nO[grow];
            ushort4 o;
            o.x = f2bf(acc[i][0] * nf); o.y = f2bf(acc[i][1] * nf);
            o.z = f2bf(acc[i][2] * nf); o.w = f2bf(acc[i][3] * nf);
            *(ushort4*)&h2[(size_t)grow * 32 + c0] = o;
        }
    }
}

// ---------------- agg2: wave/node, uint4 = 16 rows in flight per VMEM -------
__global__ void k_agg32(const unsigned short* __restrict__ h,
                        const int* __restrict__ csrc,
                        const int* __restrict__ ostart, const int* __restrict__ oend,
                        const float* __restrict__ nI, const float* __restrict__ b2,
                        float* __restrict__ out, int n) {
    int node = blockIdx.x * 4 + (threadIdx.x >> 6);
    int lane = threadIdx.x & 63;
    if (node >= n) return;
    int s0 = ostart[node], s1 = oend[node];
    int sub = lane >> 2;                         // 16 edge slots
    int c8 = (lane & 3) * 8;                     // 8 cols/lane (uint4 = 16B)
    float a[8] = {};
    int e = s0;
    for (; e + 15 < s1; e += 16) {               // 16 edges, 1 uint4/lane
        int p = csrc[e + sub] & SRCMASK;
        uint4 u = *(const uint4*)&h[(size_t)p * 32 + c8];
        a[0] += bflo(u.x); a[1] += bfhi(u.x);
        a[2] += bflo(u.y); a[3] += bfhi(u.y);
        a[4] += bflo(u.z); a[5] += bfhi(u.z);
        a[6] += bflo(u.w); a[7] += bfhi(u.w);
    }
    for (; e < s1; e += 16) {                    // tail, guarded (<=1 pass)
        if (e + sub < s1) {
            int p = csrc[e + sub] & SRCMASK;
            uint4 u = *(const uint4*)&h[(size_t)p * 32 + c8];
            a[0] += bflo(u.x); a[1] += bfhi(u.x);
            a[2] += bflo(u.y); a[3] += bfhi(u.y);
            a[4] += bflo(u.z); a[5] += bfhi(u.z);
            a[6] += bflo(u.w); a[7] += bfhi(u.w);
        }
    }
#pragma unroll
    for (int i = 0; i < 8; i++) {                // reduce over 16 subs
        a[i] += __shfl(a[i], lane ^ 4, 64);
        a[i] += __shfl(a[i], lane ^ 8, 64);
        a[i] += __shfl(a[i], lane ^ 16, 64);
        a[i] += __shfl(a[i], lane ^ 32, 64);
    }
    if (sub == 0) {                              // lanes 0-3 -> 32 cols
        float ni = nI[node];
        float4 o0, o1;
        o0.x = fmaf(a[0], ni, b2[c8 + 0]);
        o0.y = fmaf(a[1], ni, b2[c8 + 1]);
        o0.z = fmaf(a[2], ni, b2[c8 + 2]);
        o0.w = fmaf(a[3], ni, b2[c8 + 3]);
        o1.x = fmaf(a[4], ni, b2[c8 + 4]);
        o1.y = fmaf(a[5], ni, b2[c8 + 5]);
        o1.z = fmaf(a[6], ni, b2[c8 + 6]);
        o1.w = fmaf(a[7], ni, b2[c8 + 7]);
        *(float4*)&out[(size_t)node * 32 + c8] = o0;
        *(float4*)&out[(size_t)node * 32 + c8 + 4] = o1;
    }
}

extern "C" void kernel_launch(void* const* d_in, const int* in_sizes, int n_in,
                              void* d_out, int out_size, void* d_ws, size_t ws_size,
                              hipStream_t stream) {
    const float* x   = (const float*)d_in[0];  // [N,128]
    const int*   src = (const int*)d_in[1];    // [E]
    const int*   dst = (const int*)d_in[2];    // [E]
    const float* W1  = (const float*)d_in[3];  // [128,64]
    const float* b1  = (const float*)d_in[4];  // [64]
    const float* W2  = (const float*)d_in[5];  // [64,32]
    const float* b2  = (const float*)d_in[6];  // [32]
    float* out = (float*)d_out;                // [N,32]

    const int N = in_sizes[0] / 128;           // 100000
    const int E = in_sizes[1];                 // 1600000
    const int NB = (N + BNODES - 1) / BNODES;  // 782 buckets
    const int NBLK = (E + CHUNK - 1) / CHUNK;  // 391 place blocks

    char* wsb = (char*)d_ws;
    float* nO     = (float*)wsb;  wsb += (size_t)N * 4;
    float* nI     = (float*)wsb;  wsb += (size_t)N * 4;
    int*   ostart = (int*)wsb;    wsb += (size_t)N * 4;
    int*   oend   = (int*)wsb;    wsb += (size_t)N * 4;
    int*   csrc   = (int*)wsb;    wsb += (size_t)NB * CAP * 4;     // 8.0 MB
    int*   offs   = (int*)wsb;    wsb += (size_t)NBLK * 801 * 4;   // 1.25 MB
    unsigned short* h1 = (unsigned short*)wsb;
                                  wsb += (size_t)N * 64 * 2;       // 12.8 MB bf16
    float* x2     = (float*)wsb;  wsb += (size_t)N * 64 * 4;       // 25.6 MB
    unsigned short* h2 = h1;      // h1 dead after k_agg64sc
    // scratch aliased into x2 (dead at sort2, before agg64sc writes x2):
    int*   ebuf   = (int*)x2;                                      // 6.4 MB
    unsigned char* sbuf = (unsigned char*)(ebuf) + (size_t)E * 4;  // 1.6 MB
    int*   soffs  = (int*)(sbuf + (size_t)E);                      // 1.25 MB

    // CSR build — no memset, no global atomics anywhere
    k_place<<<NBLK, 1024, 0, stream>>>(src, dst, ebuf, sbuf, offs, soffs, E);
    k_sort2<<<NB, 1024, 0, stream>>>(ebuf, sbuf, offs, soffs, csrc,
                                     ostart, oend, nI, nO, N, NBLK);

    // layer 1 (h1 + x2 slice-major [4][N][16]; scatter-to-LDS aggregation)
    k_gemm1<<<(N + 63) / 64, 256, 0, stream>>>(x, W1, nO, h1, N);
    k_agg64sc<<<NB * 4, 256, 0, stream>>>(h1, csrc, oend, nI, b1, x2, N);

    // layer 2
    k_gemm2<<<(N + 127) / 128, 256, 0, stream>>>(x2, W2, nO, h2, N);
    k_agg32<<<(N + 3) / 4, 256, 0, stream>>>(h2, csrc, ostart, oend, nI, b2, out, N);
}

// Round 8
// 305.101 us; speedup vs baseline: 2.5860x; 2.5860x over previous
//
#include <hip/hip_runtime.h>
#include <hip/hip_bf16.h>

// GNN: 2-layer GraphConv (DGL norm='both'), N=100000, E=1600000.
// Round 22: revert r21's cooperative fusion (failed: coop launch never ran;
// absmax=bias-only). Back to r18 baseline (293.7us passing) + a fusion that
// needs NO grid sync: gemm2 is row-wise (h2[i] = nO[i]*(x2[i]@W2)), and
// k_agg64's wave holds the full x2 row in registers after its butterfly
// reduce (all 64 lanes replicated; lane octet q=lane&7 = cols 8q..8q+7).
// So agg64's epilogue computes the 64->32 matvec in-wave: W2T in LDS
// (32x68 pad -> ~2-way conflicts, 16B-aligned b128 reads), 8 ds_read_b128 +
// 32 FMA + 12 shfl per node, q==0 lanes store ushort4 h2. Deletes: x2
// buffer (25.6MB write + 25.6MB read), gemm2 kernel, one launch. h2 now
// lives in the old ebuf scratch (dead after sort2) -- NOT aliased to h1,
// which agg64g2 still reads. CSR build + gemm1 + agg32 unchanged from r18.

#define BSH 7                 // 128 nodes per bucket
#define BNODES 128
#define SRCMASK 0x1FFFF       // src < 131072
#define CAP 2560              // csrc bucket capacity (mean 2048, sigma~45)
#define CHUNK 4096            // edges per place-block (391 blocks)

__device__ __forceinline__ unsigned short f2bf(float f) {
    unsigned int u = __float_as_uint(f);
    return (unsigned short)((u + 0x7FFFu + ((u >> 16) & 1u)) >> 16);  // RNE
}

__device__ __forceinline__ float bflo(unsigned int u) {
    return __uint_as_float(u << 16);
}
__device__ __forceinline__ float bfhi(unsigned int u) {
    return __uint_as_float(u & 0xFFFF0000u);
}

// ---------------- place: block-local dual counting sort ---------------------
__global__ __launch_bounds__(1024) void k_place(const int* __restrict__ src,
        const int* __restrict__ dst, int* __restrict__ ebuf,
        unsigned char* __restrict__ sbuf, int* __restrict__ offs,
        int* __restrict__ soffs, int E) {
    __shared__ int lh[800], s[800];
    int t = threadIdx.x;
    int e0 = blockIdx.x * CHUNK;
    int e1 = min(e0 + CHUNK, E);
    if (t < 800) lh[t] = 0;
    __syncthreads();
    for (int i = e0 + t; i < e1; i += 1024) {
        atomicAdd(&lh[dst[i] >> BSH], 0x10000);
        atomicAdd(&lh[src[i] >> BSH], 1);
    }
    __syncthreads();
    if (t < 800) s[t] = lh[t];
    __syncthreads();
    for (int o = 1; o < 800; o <<= 1) {            // packed inclusive scan
        int u = (t < 800 && t >= o) ? s[t - o] : 0;
        __syncthreads();
        if (t < 800) s[t] += u;
        __syncthreads();
    }
    int obase = blockIdx.x * 801;
    if (t < 800) {
        int incl = s[t], c = lh[t];
        int bd = (incl >> 16) - (c >> 16);         // exclusive dst base
        int bs = (incl & 0xFFFF) - (c & 0xFFFF);   // exclusive src base
        offs[obase + t] = bd;
        soffs[obase + t] = bs;
        s[t] = (bd << 16) | bs;                    // packed cursors
    }
    if (t == 0) { offs[obase + 800] = e1 - e0; soffs[obase + 800] = e1 - e0; }
    __syncthreads();
    for (int i = e0 + t; i < e1; i += 1024) {
        int sv = src[i], d = dst[i];               // L2-hot from phase 1
        int pd = atomicAdd(&s[d >> BSH], 0x10000) >> 16;
        ebuf[e0 + pd] = sv | ((d & (BNODES - 1)) << 17);
        int ps = atomicAdd(&s[sv >> BSH], 1) & 0xFFFF;
        sbuf[e0 + ps] = (unsigned char)(sv & (BNODES - 1));
    }
}

// ---------------- sort2: segments -> CSR + nI + nO (no global atomics) ------
__global__ __launch_bounds__(1024) void k_sort2(const int* __restrict__ ebuf,
        const unsigned char* __restrict__ sbuf, const int* __restrict__ offs,
        const int* __restrict__ soffs, int* __restrict__ csrc,
        int* __restrict__ ostart, int* __restrict__ oend,
        float* __restrict__ nI, float* __restrict__ nO, int n, int NBLK) {
    __shared__ int cnt[BNODES], cur[BNODES], s[BNODES], scnt[BNODES];
    __shared__ int segst[400], segen[400], sst[400], sen[400];
    int t = threadIdx.x, b = blockIdx.x;
    if (t < NBLK) {
        segst[t] = t * CHUNK + offs[t * 801 + b];
        segen[t] = t * CHUNK + offs[t * 801 + b + 1];
        sst[t]   = t * CHUNK + soffs[t * 801 + b];
        sen[t]   = t * CHUNK + soffs[t * 801 + b + 1];
    }
    if (t < BNODES) { cnt[t] = 0; scnt[t] = 0; }
    __syncthreads();
    int grp = t >> 3, ln = t & 7;                  // 128 groups x 8 lanes
    for (int sg = grp; sg < NBLK; sg += 128) {
        int en = segen[sg];
        for (int i = segst[sg] + ln; i < en; i += 8)
            atomicAdd(&cnt[ebuf[i] >> 17], 1);
        int en2 = sen[sg];
        for (int i = sst[sg] + ln; i < en2; i += 8)
            atomicAdd(&scnt[sbuf[i]], 1);
    }
    __syncthreads();
    if (t < BNODES) s[t] = cnt[t];
    __syncthreads();
    for (int o = 1; o < BNODES; o <<= 1) {
        int u = (t < BNODES && t >= o) ? s[t - o] : 0;
        __syncthreads();
        if (t < BNODES) s[t] += u;
        __syncthreads();
    }
    if (t < BNODES) {
        int e0 = b * CAP;
        int st = e0 + s[t] - cnt[t];
        cur[t] = st;
        int g = b * BNODES + t;
        if (g < n) {
            ostart[g] = st;
            oend[g] = e0 + s[t];
            nI[g] = rsqrtf(fmaxf((float)cnt[t], 1.0f));
            nO[g] = rsqrtf(fmaxf((float)scnt[t], 1.0f));
        }
    }
    __syncthreads();
    for (int sg = grp; sg < NBLK; sg += 128) {
        int en = segen[sg];
        for (int i = segst[sg] + ln; i < en; i += 8) {
            int p = ebuf[i];                       // L2-hot from pass 1
            int pos = atomicAdd(&cur[p >> 17], 1);
            csrc[pos] = p & SRCMASK;
        }
    }
}

// ---------------- GEMM1: h1(bf16) = (x*nO) @ W1, 128->64 --------------------
__global__ __launch_bounds__(256) void k_gemm1(const float* __restrict__ x,
                        const float* __restrict__ W1, const float* __restrict__ nO,
                        unsigned short* __restrict__ h1, int n) {
    __shared__ float sX[64 * 132];
    __shared__ float sW[128 * 64];
    const int t = threadIdx.x;
    {
        const float4* W4 = (const float4*)W1;
        float4* sW4 = (float4*)sW;
#pragma unroll
        for (int i = 0; i < 8; i++) sW4[t + 256 * i] = W4[t + 256 * i];
    }
    const int rowbase = blockIdx.x * 64;
    {
        const float4* x4 = (const float4*)x;
        float4* sX4 = (float4*)sX;
#pragma unroll
        for (int i = 0; i < 8; i++) {
            int f = t + 256 * i;
            int row = f >> 5, kc = f & 31;
            int grow = rowbase + row;
            float4 v = make_float4(0.f, 0.f, 0.f, 0.f);
            if (grow < n) v = x4[(size_t)grow * 32 + kc];
            sX4[row * 33 + kc] = v;
        }
    }
    __syncthreads();
    const int lane = t & 63, wv = t >> 6;
    const int rg = lane >> 2, cg = lane & 3;
    const int c0 = wv * 16 + cg * 4;
    float acc[4][4] = {};
    for (int kk = 0; kk < 128; kk += 4) {
        float xr[4][4], wr[4][4];
#pragma unroll
        for (int i = 0; i < 4; i++)
            *(float4*)xr[i] = *(const float4*)&sX[(rg + 16 * i) * 132 + kk];
#pragma unroll
        for (int j = 0; j < 4; j++)
            *(float4*)wr[j] = *(const float4*)&sW[(kk + j) * 64 + c0];
#pragma unroll
        for (int j = 0; j < 4; j++)
#pragma unroll
            for (int i = 0; i < 4; i++)
#pragma unroll
                for (int c = 0; c < 4; c++)
                    acc[i][c] = fmaf(xr[i][j], wr[j][c], acc[i][c]);
    }
#pragma unroll
    for (int i = 0; i < 4; i++) {
        int grow = rowbase + rg + 16 * i;
        if (grow < n) {
            float nf = nO[grow];
            ushort4 o;
            o.x = f2bf(acc[i][0] * nf); o.y = f2bf(acc[i][1] * nf);
            o.z = f2bf(acc[i][2] * nf); o.w = f2bf(acc[i][3] * nf);
            *(ushort4*)&h1[(size_t)grow * 64 + c0] = o;
        }
    }
}

// ---------------- agg1+gemm2 fused: gather h1, reduce, in-wave matvec -------
// Gather/reduce identical to r18 agg64. After the butterfly, every lane
// holds the node's full x2 row for its octet q=lane&7 (cols 8q..8q+7).
// Epilogue: v = relu(a*nI + b1); matvec vs W2T in LDS (32x68 pad);
// reduce partials across q (xor 1,2,4); q==0 lanes store ushort4 h2 =
// bf16(nO * (x2 @ W2)). x2 never touches memory.
__global__ __launch_bounds__(256) void k_agg64g2(const unsigned short* __restrict__ h,
        const int* __restrict__ csrc,
        const int* __restrict__ ostart, const int* __restrict__ oend,
        const float* __restrict__ nI, const float* __restrict__ nO,
        const float* __restrict__ b1, const float* __restrict__ W2,
        unsigned short* __restrict__ h2, int n) {
    __shared__ float sWT[32 * 68];                 // W2 transposed, padded
    {
        int t = threadIdx.x;
        for (int i = t; i < 2048; i += 256) {
            int cc = i & 31, k = i >> 5;           // coalesced W2 read
            sWT[cc * 68 + k] = W2[(size_t)k * 32 + cc];
        }
    }
    __syncthreads();
    int node = blockIdx.x * 4 + (threadIdx.x >> 6);
    int lane = threadIdx.x & 63;
    if (node >= n) return;
    int s0 = ostart[node], s1 = oend[node];
    int sub = lane >> 3;                         // 8 edge slots
    int q = lane & 7;
    int c8 = q * 8;                              // 8 cols/lane (uint4 = 16B)
    float a[8] = {}, d[8] = {};
    int e = s0;
    for (; e + 15 < s1; e += 16) {               // 16 edges, 2 uint4/lane
        int p0 = csrc[e + sub];
        int p1 = csrc[e + 8 + sub];
        uint4 u0 = *(const uint4*)&h[(size_t)p0 * 64 + c8];
        uint4 u1 = *(const uint4*)&h[(size_t)p1 * 64 + c8];
        a[0] += bflo(u0.x); a[1] += bfhi(u0.x);
        a[2] += bflo(u0.y); a[3] += bfhi(u0.y);
        a[4] += bflo(u0.z); a[5] += bfhi(u0.z);
        a[6] += bflo(u0.w); a[7] += bfhi(u0.w);
        d[0] += bflo(u1.x); d[1] += bfhi(u1.x);
        d[2] += bflo(u1.y); d[3] += bfhi(u1.y);
        d[4] += bflo(u1.z); d[5] += bfhi(u1.z);
        d[6] += bflo(u1.w); d[7] += bfhi(u1.w);
    }
    for (; e < s1; e += 8) {                     // tail, guarded
        if (e + sub < s1) {
            int p = csrc[e + sub];
            uint4 u = *(const uint4*)&h[(size_t)p * 64 + c8];
            a[0] += bflo(u.x); a[1] += bfhi(u.x);
            a[2] += bflo(u.y); a[3] += bfhi(u.y);
            a[4] += bflo(u.z); a[5] += bfhi(u.z);
            a[6] += bflo(u.w); a[7] += bfhi(u.w);
        }
    }
#pragma unroll
    for (int i = 0; i < 8; i++) a[i] += d[i];
#pragma unroll
    for (int i = 0; i < 8; i++) {                // reduce over 8 subs
        a[i] += __shfl(a[i], lane ^ 8, 64);
        a[i] += __shfl(a[i], lane ^ 16, 64);
        a[i] += __shfl(a[i], lane ^ 32, 64);
    }
    // ---- layer-1 epilogue in-register: v = relu(a*nI + b1[c8..]) ----
    float ni = nI[node];
    float v[8];
#pragma unroll
    for (int i = 0; i < 8; i++)
        v[i] = fmaxf(fmaf(a[i], ni, b1[c8 + i]), 0.f);
    // ---- in-wave gemm2: p[c] = sum_k x2[k] * W2[k][4*sub+c] ----
    float p4[4];
#pragma unroll
    for (int c = 0; c < 4; c++) {
        const float* wr = &sWT[(sub * 4 + c) * 68 + c8];
        float4 wlo = *(const float4*)&wr[0];
        float4 whi = *(const float4*)&wr[4];
        float pc;
        pc = v[0] * wlo.x;
        pc = fmaf(v[1], wlo.y, pc);
        pc = fmaf(v[2], wlo.z, pc);
        pc = fmaf(v[3], wlo.w, pc);
        pc = fmaf(v[4], whi.x, pc);
        pc = fmaf(v[5], whi.y, pc);
        pc = fmaf(v[6], whi.z, pc);
        pc = fmaf(v[7], whi.w, pc);
        p4[c] = pc;
    }
#pragma unroll
    for (int c = 0; c < 4; c++) {                // reduce over 8 octets q
        p4[c] += __shfl(p4[c], lane ^ 1, 64);
        p4[c] += __shfl(p4[c], lane ^ 2, 64);
        p4[c] += __shfl(p4[c], lane ^ 4, 64);
    }
    if (q == 0) {                                // 8 lanes -> 32 cols
        float nOv = nO[node];
        ushort4 o;
        o.x = f2bf(p4[0] * nOv); o.y = f2bf(p4[1] * nOv);
        o.z = f2bf(p4[2] * nOv); o.w = f2bf(p4[3] * nOv);
        *(ushort4*)&h2[(size_t)node * 32 + sub * 4] = o;
    }
}

// ---------------- agg2: wave/node, uint4 = 16 rows in flight per VMEM -------
__global__ void k_agg32(const unsigned short* __restrict__ h,
                        const int* __restrict__ csrc,
                        const int* __restrict__ ostart, const int* __restrict__ oend,
                        const float* __restrict__ nI, const float* __restrict__ b2,
                        float* __restrict__ out, int n) {
    int node = blockIdx.x * 4 + (threadIdx.x >> 6);
    int lane = threadIdx.x & 63;
    if (node >= n) return;
    int s0 = ostart[node], s1 = oend[node];
    int sub = lane >> 2;                         // 16 edge slots
    int c8 = (lane & 3) * 8;                     // 8 cols/lane (uint4 = 16B)
    float a[8] = {};
    int e = s0;
    for (; e + 15 < s1; e += 16) {               // 16 edges, 1 uint4/lane
        int p = csrc[e + sub];
        uint4 u = *(const uint4*)&h[(size_t)p * 32 + c8];
        a[0] += bflo(u.x); a[1] += bfhi(u.x);
        a[2] += bflo(u.y); a[3] += bfhi(u.y);
        a[4] += bflo(u.z); a[5] += bfhi(u.z);
        a[6] += bflo(u.w); a[7] += bfhi(u.w);
    }
    for (; e < s1; e += 16) {                    // tail, guarded (<=1 pass)
        if (e + sub < s1) {
            int p = csrc[e + sub];
            uint4 u = *(const uint4*)&h[(size_t)p * 32 + c8];
            a[0] += bflo(u.x); a[1] += bfhi(u.x);
            a[2] += bflo(u.y); a[3] += bfhi(u.y);
            a[4] += bflo(u.z); a[5] += bfhi(u.z);
            a[6] += bflo(u.w); a[7] += bfhi(u.w);
        }
    }
#pragma unroll
    for (int i = 0; i < 8; i++) {                // reduce over 16 subs
        a[i] += __shfl(a[i], lane ^ 4, 64);
        a[i] += __shfl(a[i], lane ^ 8, 64);
        a[i] += __shfl(a[i], lane ^ 16, 64);
        a[i] += __shfl(a[i], lane ^ 32, 64);
    }
    if (sub == 0) {                              // lanes 0-3 -> 32 cols
        float ni = nI[node];
        float4 o0, o1;
        o0.x = fmaf(a[0], ni, b2[c8 + 0]);
        o0.y = fmaf(a[1], ni, b2[c8 + 1]);
        o0.z = fmaf(a[2], ni, b2[c8 + 2]);
        o0.w = fmaf(a[3], ni, b2[c8 + 3]);
        o1.x = fmaf(a[4], ni, b2[c8 + 4]);
        o1.y = fmaf(a[5], ni, b2[c8 + 5]);
        o1.z = fmaf(a[6], ni, b2[c8 + 6]);
        o1.w = fmaf(a[7], ni, b2[c8 + 7]);
        *(float4*)&out[(size_t)node * 32 + c8] = o0;
        *(float4*)&out[(size_t)node * 32 + c8 + 4] = o1;
    }
}

extern "C" void kernel_launch(void* const* d_in, const int* in_sizes, int n_in,
                              void* d_out, int out_size, void* d_ws, size_t ws_size,
                              hipStream_t stream) {
    const float* x   = (const float*)d_in[0];  // [N,128]
    const int*   src = (const int*)d_in[1];    // [E]
    const int*   dst = (const int*)d_in[2];    // [E]
    const float* W1  = (const float*)d_in[3];  // [128,64]
    const float* b1  = (const float*)d_in[4];  // [64]
    const float* W2  = (const float*)d_in[5];  // [64,32]
    const float* b2  = (const float*)d_in[6];  // [32]
    float* out = (float*)d_out;                // [N,32]

    const int N = in_sizes[0] / 128;           // 100000
    const int E = in_sizes[1];                 // 1600000
    const int NB = (N + BNODES - 1) / BNODES;  // 782 buckets
    const int NBLK = (E + CHUNK - 1) / CHUNK;  // 391 place blocks

    char* wsb = (char*)d_ws;
    float* nO     = (float*)wsb;  wsb += (size_t)N * 4;
    float* nI     = (float*)wsb;  wsb += (size_t)N * 4;
    int*   ostart = (int*)wsb;    wsb += (size_t)N * 4;
    int*   oend   = (int*)wsb;    wsb += (size_t)N * 4;
    int*   csrc   = (int*)wsb;    wsb += (size_t)NB * CAP * 4;     // 8.0 MB
    int*   offs   = (int*)wsb;    wsb += (size_t)NBLK * 801 * 4;   // 1.25 MB
    unsigned short* h1 = (unsigned short*)wsb;
                                  wsb += (size_t)N * 64 * 2;       // 12.8 MB bf16
    char*  scr    = wsb;          wsb += (size_t)E * 4 + E + (size_t)NBLK * 801 * 4;
    // scratch region: ebuf/sbuf/soffs live only until sort2; h2 reuses it
    int*   ebuf   = (int*)scr;                                     // 6.4 MB
    unsigned char* sbuf = (unsigned char*)scr + (size_t)E * 4;     // 1.6 MB
    int*   soffs  = (int*)((char*)scr + (size_t)E * 4 + E);        // 1.25 MB
    unsigned short* h2 = (unsigned short*)scr;   // 6.4 MB, after sort2 done
    // NOTE: h2 must NOT alias h1 (agg64g2 reads h1 while writing h2)

    // CSR build — no memset, no global atomics anywhere
    k_place<<<NBLK, 1024, 0, stream>>>(src, dst, ebuf, sbuf, offs, soffs, E);
    k_sort2<<<NB, 1024, 0, stream>>>(ebuf, sbuf, offs, soffs, csrc,
                                     ostart, oend, nI, nO, N, NBLK);

    // layer 1 + gemm2 fused into the aggregation epilogue
    k_gemm1<<<(N + 63) / 64, 256, 0, stream>>>(x, W1, nO, h1, N);
    k_agg64g2<<<(N + 3) / 4, 256, 0, stream>>>(h1, csrc, ostart, oend,
                                               nI, nO, b1, W2, h2, N);

    // layer 2 aggregation
    k_agg32<<<(N + 3) / 4, 256, 0, stream>>>(h2, csrc, ostart, oend, nI, b2, out, N);
}